// Round 9
// baseline (734.126 us; speedup 1.0000x reference)
//
#include <hip/hip_runtime.h>
#include <hip/hip_bf16.h>

typedef float  f32x4 __attribute__((ext_vector_type(4)));
typedef short  s16x8 __attribute__((ext_vector_type(8)));
typedef short  s16x4 __attribute__((ext_vector_type(4)));

#define NEGBIG -1e30f

__device__ __forceinline__ unsigned short f2b(float f) {
    union { float f; unsigned u; } c; c.f = f;
    unsigned r = c.u + 0x7FFF + ((c.u >> 16) & 1);
    return (unsigned short)(r >> 16);
}
__device__ __forceinline__ float b2f(unsigned short h) {
    union { unsigned u; float f; } c; c.u = ((unsigned)h) << 16;
    return c.f;
}
__device__ __forceinline__ float sigm(float x) { return 1.f / (1.f + __expf(-x)); }

// coherent (agent-scope) accessors: bypass per-XCD L1/L2, hit the memory-side coherence point.
__device__ __forceinline__ s16x8 ld_b128_sc(const unsigned short* p) {
    s16x8 r;
    asm volatile("global_load_dwordx4 %0, %1, off sc0 sc1" : "=v"(r) : "v"(p));
    return r;
}
__device__ __forceinline__ void st_b64_sc(unsigned short* p, unsigned int x, unsigned int y) {
    union { unsigned int u[2]; unsigned long long ull; } v; v.u[0] = x; v.u[1] = y;
    asm volatile("global_store_dwordx2 %0, %1, off sc0 sc1" :: "v"(p), "v"(v.ull) : "memory");
}
__device__ __forceinline__ void st_b128f_sc(float* p, f32x4 v) {
    asm volatile("global_store_dwordx4 %0, %1, off sc0 sc1" :: "v"(p), "v"(v) : "memory");
}

// ---------------------------------------------------------------- fused prep: init + weight casts + E^T build
__global__ __launch_bounds__(256) void prep_all(const float* code_emb, const int* ct0, const int* ct1, const int* ct2,
                                                const float* t0e, const float* t1e, const float* t2e,
                                                const float* Wq, const float* Wk, const float* Wv,
                                                const float* gWih, const float* gWhh,
                                                unsigned short* ET, unsigned short* wcat,
                                                unsigned short* wih, unsigned short* whh,
                                                int* flags, unsigned short* hb0) {
    __shared__ float tile[64][65];
    const int bid = blockIdx.x;
    const int t = threadIdx.x;
    if (bid < 256) {
        const int d0 = (bid & 3) * 64, c0 = (bid >> 2) * 64;
        for (int p = 0; p < 16; ++p) {
            int idx = p * 256 + t;
            int dl = idx & 63, cl = idx >> 6;
            int code = c0 + cl + 1;
            int d = d0 + dl;
            float v = code_emb[code * 256 + d] + t0e[ct0[code] * 256 + d]
                    + t1e[ct1[code] * 256 + d] + t2e[ct2[code] * 256 + d];
            tile[dl][cl] = v;
        }
        __syncthreads();
        for (int p = 0; p < 2; ++p) {
            int idx = p * 256 + t;
            int dl = idx >> 3, ch = idx & 7;
            s16x8 pk;
#pragma unroll
            for (int e = 0; e < 8; ++e) pk[e] = (short)f2b(tile[dl][ch * 8 + e]);
            *(s16x8*)(ET + (size_t)(d0 + dl) * 4096 + c0 + ch * 8) = pk;
        }
    } else {
        if (bid >= 504) {
            int idx = (bid - 504) * 256 + t;
            for (int i = idx; i < 1024; i += 2048) flags[i] = 0;
            for (int i = idx; i < 32768; i += 2048) hb0[i] = 0;
        }
        int idx = (bid - 256) * 256 + t;
        const int stride = 256 * 256;
        const int N1 = 131072, N2 = 491520, N3 = 786432;
        for (; idx < N1 + N2 + N3; idx += stride) {
            if (idx < N1) {
                int n = idx >> 8, k = idx & 255;
                float v;
                if (n < 128) v = Wq[k * 128 + n];
                else if (n < 256) v = Wk[k * 128 + (n - 128)];
                else v = Wv[k * 256 + (n - 256)];
                wcat[n * 256 + k] = f2b(v);
            } else if (idx < N1 + N2) {
                int i = idx - N1; wih[i] = f2b(gWih[i]);
            } else {
                int i = idx - N1 - N2; whh[i] = f2b(gWhh[i]);
            }
        }
    }
}

// ---------------------------------------------------------------- encoder GEMM (2-deep register prefetch)
__global__ __launch_bounds__(256) void enc_gemm(const float* code_x, const unsigned short* ET,
                                                const int* lens, unsigned short* Vb) {
    __shared__ __align__(16) char sm[4096 + 32768 + 128];
    char* As = sm;
    char* Bs = sm + 4096;
    float* cl = (float*)(sm + 4096 + 32768);
    const int m0 = blockIdx.x * 32;
    const int t = threadIdx.x, l = t & 63, w = t >> 6;
    const int lr = l & 15, lq = l >> 4, l7 = l & 7;
    const int sr = t >> 3, sc = t & 7;
    const int bn = t >> 3, bc = t & 7;
    const float* gabase = code_x + (size_t)(m0 + sr) * 4096 + sc * 8;
    f32x4 acc[2][4];
#pragma unroll
    for (int a = 0; a < 2; ++a)
#pragma unroll
        for (int b = 0; b < 4; ++b) acc[a][b] = (f32x4){0.f, 0.f, 0.f, 0.f};
    int cnt = 0;

    f32x4 a0A, a1A, a0B, a1B;
    s16x8 bA[8], bB[8];

#define ENC_ISSUE(SLOT, IT) do {                                                     \
    const int k0_ = (IT) * 64;                                                       \
    a0##SLOT = *(const f32x4*)(gabase + k0_);                                        \
    a1##SLOT = *(const f32x4*)(gabase + k0_ + 4);                                    \
    _Pragma("unroll")                                                                \
    for (int rd_ = 0; rd_ < 8; ++rd_)                                                \
        b##SLOT[rd_] = *(const s16x8*)(ET + (size_t)(rd_ * 32 + bn) * 4096 + k0_ + bc * 8); \
} while (0)

#define ENC_CONSUME(SLOT, NEXTIT) do {                                               \
    s16x8 ap_;                                                                       \
    _Pragma("unroll")                                                                \
    for (int e_ = 0; e_ < 4; ++e_) { bool on_ = a0##SLOT[e_] > 0.f; ap_[e_] = on_ ? (short)0x3F80 : (short)0; cnt += on_ ? 1 : 0; } \
    _Pragma("unroll")                                                                \
    for (int e_ = 0; e_ < 4; ++e_) { bool on_ = a1##SLOT[e_] > 0.f; ap_[4 + e_] = on_ ? (short)0x3F80 : (short)0; cnt += on_ ? 1 : 0; } \
    *(s16x8*)(As + sr * 128 + ((sc ^ (sr & 7)) << 4)) = ap_;                         \
    _Pragma("unroll")                                                                \
    for (int rd_ = 0; rd_ < 8; ++rd_) {                                              \
        int n_ = rd_ * 32 + bn;                                                      \
        *(s16x8*)(Bs + n_ * 128 + ((bc ^ (n_ & 7)) << 4)) = b##SLOT[rd_];            \
    }                                                                                \
    if ((NEXTIT) < 64) ENC_ISSUE(SLOT, NEXTIT);                                      \
    __syncthreads();                                                                 \
    _Pragma("unroll")                                                                \
    for (int kk_ = 0; kk_ < 2; ++kk_) {                                              \
        const int cp_ = kk_ * 4 + lq;                                                \
        s16x8 af_[2], bf_[4];                                                        \
        _Pragma("unroll")                                                            \
        for (int mt_ = 0; mt_ < 2; ++mt_)                                            \
            af_[mt_] = *(const s16x8*)(As + (mt_ * 16 + lr) * 128 + ((cp_ ^ l7) << 4)); \
        _Pragma("unroll")                                                            \
        for (int nt_ = 0; nt_ < 4; ++nt_)                                            \
            bf_[nt_] = *(const s16x8*)(Bs + ((w * 4 + nt_) * 16 + lr) * 128 + ((cp_ ^ l7) << 4)); \
        _Pragma("unroll")                                                            \
        for (int mt_ = 0; mt_ < 2; ++mt_)                                            \
            _Pragma("unroll")                                                        \
            for (int nt_ = 0; nt_ < 4; ++nt_)                                        \
                acc[mt_][nt_] = __builtin_amdgcn_mfma_f32_16x16x32_bf16(af_[mt_], bf_[nt_], acc[mt_][nt_], 0, 0, 0); \
    }                                                                                \
    __syncthreads();                                                                 \
} while (0)

    ENC_ISSUE(A, 0);
    ENC_ISSUE(B, 1);
    for (int base = 0; base < 64; base += 2) {
        ENC_CONSUME(A, base + 2);
        ENC_CONSUME(B, base + 3);
    }
#undef ENC_ISSUE
#undef ENC_CONSUME

    float fc = (float)cnt;
    fc += __shfl_xor(fc, 1); fc += __shfl_xor(fc, 2); fc += __shfl_xor(fc, 4);
    if (sc == 0) cl[sr] = fmaxf(fc, 1.f);
    __syncthreads();
#pragma unroll
    for (int mt = 0; mt < 2; ++mt)
#pragma unroll
        for (int i = 0; i < 4; ++i) {
            int m = mt * 16 + lq * 4 + i;
            int gm = m0 + m;
            float rc = 1.f / cl[m];
            unsigned bi = (unsigned)gm / 100u;
            unsigned vi = (unsigned)gm - bi * 100u;
            float msk = ((int)vi < lens[bi]) ? 1.f : 0.f;
#pragma unroll
            for (int nt = 0; nt < 4; ++nt) {
                int n = (w * 4 + nt) * 16 + lr;
                Vb[(size_t)gm * 256 + n] = f2b(acc[mt][nt][i] * rc * msk);
            }
        }
}

// ---------------------------------------------------------------- generic bf16 GEMM (2-deep register prefetch)
__global__ __launch_bounds__(256) void gemm_bf16(const unsigned short* A, const unsigned short* Bm,
                                                 int K, int Ntot, int mode,
                                                 unsigned short* outp, const float* bias) {
    __shared__ __align__(16) char sm[4096 + 32768];
    char* As = sm;
    char* Bs = sm + 4096;
    const int m0 = blockIdx.x * 32;
    const int n0 = blockIdx.y * 256;
    const int t = threadIdx.x, l = t & 63, w = t >> 6;
    const int lr = l & 15, lq = l >> 4, l7 = l & 7;
    const int sr = t >> 3, sc = t & 7;
    const int bn = t >> 3, bc = t & 7;
    const int iters = K >> 6;
    f32x4 acc[2][4];
#pragma unroll
    for (int a = 0; a < 2; ++a)
#pragma unroll
        for (int b = 0; b < 4; ++b) acc[a][b] = (f32x4){0.f, 0.f, 0.f, 0.f};

    s16x8 avA, avB;
    s16x8 bA[8], bB[8];

#define GB_ISSUE(SLOT, IT) do {                                                      \
    const int k0_ = (IT) * 64;                                                       \
    av##SLOT = *(const s16x8*)(A + (size_t)(m0 + sr) * K + k0_ + sc * 8);            \
    _Pragma("unroll")                                                                \
    for (int rd_ = 0; rd_ < 8; ++rd_)                                                \
        b##SLOT[rd_] = *(const s16x8*)(Bm + (size_t)(n0 + rd_ * 32 + bn) * K + k0_ + bc * 8); \
} while (0)

#define GB_CONSUME(SLOT, NEXTIT) do {                                                \
    *(s16x8*)(As + sr * 128 + ((sc ^ (sr & 7)) << 4)) = av##SLOT;                    \
    _Pragma("unroll")                                                                \
    for (int rd_ = 0; rd_ < 8; ++rd_) {                                              \
        int n_ = rd_ * 32 + bn;                                                      \
        *(s16x8*)(Bs + n_ * 128 + ((bc ^ (n_ & 7)) << 4)) = b##SLOT[rd_];            \
    }                                                                                \
    if ((NEXTIT) < iters) GB_ISSUE(SLOT, NEXTIT);                                    \
    __syncthreads();                                                                 \
    _Pragma("unroll")                                                                \
    for (int kk_ = 0; kk_ < 2; ++kk_) {                                              \
        const int cp_ = kk_ * 4 + lq;                                                \
        s16x8 af_[2], bf_[4];                                                        \
        _Pragma("unroll")                                                            \
        for (int mt_ = 0; mt_ < 2; ++mt_)                                            \
            af_[mt_] = *(const s16x8*)(As + (mt_ * 16 + lr) * 128 + ((cp_ ^ l7) << 4)); \
        _Pragma("unroll")                                                            \
        for (int nt_ = 0; nt_ < 4; ++nt_)                                            \
            bf_[nt_] = *(const s16x8*)(Bs + ((w * 4 + nt_) * 16 + lr) * 128 + ((cp_ ^ l7) << 4)); \
        _Pragma("unroll")                                                            \
        for (int mt_ = 0; mt_ < 2; ++mt_)                                            \
            _Pragma("unroll")                                                        \
            for (int nt_ = 0; nt_ < 4; ++nt_)                                        \
                acc[mt_][nt_] = __builtin_amdgcn_mfma_f32_16x16x32_bf16(af_[mt_], bf_[nt_], acc[mt_][nt_], 0, 0, 0); \
    }                                                                                \
    __syncthreads();                                                                 \
} while (0)

    GB_ISSUE(A, 0);
    if (iters > 1) GB_ISSUE(B, 1);
    for (int base = 0; base < iters; base += 2) {
        GB_CONSUME(A, base + 2);
        if (base + 1 < iters) GB_CONSUME(B, base + 3);
    }
#undef GB_ISSUE
#undef GB_CONSUME

#pragma unroll
    for (int mt = 0; mt < 2; ++mt)
#pragma unroll
        for (int i = 0; i < 4; ++i) {
            int gm = m0 + mt * 16 + lq * 4 + i;
#pragma unroll
            for (int nt = 0; nt < 4; ++nt) {
                int n = n0 + (w * 4 + nt) * 16 + lr;
                float v = acc[mt][nt][i];
                if (mode == 1) v += bias[n];
                outp[(size_t)gm * Ntot + n] = f2b(v);
            }
        }
}

// ---------------------------------------------------------------- attention (block per (batch, d-half)) + time-emb concat
__global__ __launch_bounds__(256) void attn_kernel(const unsigned short* QKV, const int* lens,
                                                   const float* intervals, const float* time_w, const float* time_b,
                                                   unsigned short* X) {
    __shared__ __align__(16) char sm[28672 + 32768];
    char* Pb = sm;
    char* VTb = sm + 28672;
    const int b = blockIdx.x;
    const int h = blockIdx.y;
    const int t = threadIdx.x, l = t & 63, w = t >> 6;
    const int lr = l & 15, lq = l >> 4;
    const int lenb = lens[b];
    for (int p = 0; p < 7; ++p) {
        int idx = p * 256 + t;
        *(f32x4*)(Pb + idx * 16) = (f32x4){0.f, 0.f, 0.f, 0.f};
    }
    __syncthreads();
    f32x4 S[2][7];
#pragma unroll
    for (int a = 0; a < 2; ++a)
#pragma unroll
        for (int c = 0; c < 7; ++c) S[a][c] = (f32x4){0.f, 0.f, 0.f, 0.f};
#pragma unroll
    for (int kk = 0; kk < 4; ++kk) {
        s16x8 qa[2], kb[7];
#pragma unroll
        for (int mi = 0; mi < 2; ++mi) {
            int mt = 2 * w + mi;
            if (mt > 6) continue;
            int row = b * 100 + mt * 16 + lr;
            qa[mi] = *(const s16x8*)(QKV + (size_t)row * 512 + kk * 32 + lq * 8);
        }
#pragma unroll
        for (int nt = 0; nt < 7; ++nt) {
            int row = b * 100 + nt * 16 + lr;
            kb[nt] = *(const s16x8*)(QKV + (size_t)row * 512 + 128 + kk * 32 + lq * 8);
        }
#pragma unroll
        for (int mi = 0; mi < 2; ++mi) {
            int mt = 2 * w + mi;
            if (mt > 6) continue;
#pragma unroll
            for (int nt = 0; nt < 7; ++nt)
                S[mi][nt] = __builtin_amdgcn_mfma_f32_16x16x32_bf16(qa[mi], kb[nt], S[mi][nt], 0, 0, 0);
        }
    }
#pragma unroll
    for (int mi = 0; mi < 2; ++mi) {
        int mt = 2 * w + mi;
        if (mt > 6) continue;
        float sv[7][4];
#pragma unroll
        for (int nt = 0; nt < 7; ++nt) {
            int j = nt * 16 + lr;
#pragma unroll
            for (int i = 0; i < 4; ++i)
                sv[nt][i] = (j < lenb) ? S[mi][nt][i] : NEGBIG;
        }
#pragma unroll
        for (int i = 0; i < 4; ++i) {
            float mx = sv[0][i];
#pragma unroll
            for (int nt = 1; nt < 7; ++nt) mx = fmaxf(mx, sv[nt][i]);
            mx = fmaxf(mx, __shfl_xor(mx, 1));
            mx = fmaxf(mx, __shfl_xor(mx, 2));
            mx = fmaxf(mx, __shfl_xor(mx, 4));
            mx = fmaxf(mx, __shfl_xor(mx, 8));
            float e[7], sum = 0.f;
#pragma unroll
            for (int nt = 0; nt < 7; ++nt) { e[nt] = __expf(sv[nt][i] - mx); sum += e[nt]; }
            sum += __shfl_xor(sum, 1);
            sum += __shfl_xor(sum, 2);
            sum += __shfl_xor(sum, 4);
            sum += __shfl_xor(sum, 8);
            float rs = 1.f / sum;
            int m = mt * 16 + lq * 4 + i;
#pragma unroll
            for (int nt = 0; nt < 7; ++nt) {
                int j = nt * 16 + lr;
                *(unsigned short*)(Pb + m * 256 + (((j >> 3) ^ (m & 7)) << 4) + ((j & 7) << 1)) = f2b(e[nt] * rs);
            }
        }
    }
    __syncthreads();
    for (int p = 0; p < 8; ++p) {
        int idx = p * 256 + t;
        *(f32x4*)(VTb + idx * 16) = (f32x4){0.f, 0.f, 0.f, 0.f};
    }
    __syncthreads();
    for (int p = 0; p < 7; ++p) {
        int ci = p * 256 + t;
        if (ci < 1600) {
            int j = ci >> 4, d8 = ci & 15;
            s16x8 vv = *(const s16x8*)(QKV + (size_t)(b * 100 + j) * 512 + 256 + h * 128 + d8 * 8);
#pragma unroll
            for (int e = 0; e < 8; ++e) {
                int dl = d8 * 8 + e;
                *(unsigned short*)(VTb + dl * 256 + (((j >> 3) ^ (dl & 7)) << 4) + ((j & 7) << 1)) = (unsigned short)vv[e];
            }
        }
    }
    __syncthreads();
    f32x4 O[2][8];
#pragma unroll
    for (int a = 0; a < 2; ++a)
#pragma unroll
        for (int c = 0; c < 8; ++c) O[a][c] = (f32x4){0.f, 0.f, 0.f, 0.f};
#pragma unroll
    for (int kk = 0; kk < 4; ++kk) {
        s16x8 pa[2];
#pragma unroll
        for (int mi = 0; mi < 2; ++mi) {
            int mt = 2 * w + mi;
            if (mt > 6) continue;
            int m = mt * 16 + lr;
            pa[mi] = *(const s16x8*)(Pb + m * 256 + (((kk * 4 + lq) ^ (m & 7)) << 4));
        }
#pragma unroll
        for (int nt = 0; nt < 8; ++nt) {
            int dl = nt * 16 + lr;
            s16x8 vb = *(const s16x8*)(VTb + dl * 256 + (((kk * 4 + lq) ^ (dl & 7)) << 4));
#pragma unroll
            for (int mi = 0; mi < 2; ++mi) {
                int mt = 2 * w + mi;
                if (mt > 6) continue;
                O[mi][nt] = __builtin_amdgcn_mfma_f32_16x16x32_bf16(pa[mi], vb, O[mi][nt], 0, 0, 0);
            }
        }
    }
#pragma unroll
    for (int mi = 0; mi < 2; ++mi) {
        int mt = 2 * w + mi;
        if (mt > 6) continue;
#pragma unroll
        for (int i = 0; i < 4; ++i) {
            int m = mt * 16 + lq * 4 + i;
            if (m < 100) {
#pragma unroll
                for (int nt = 0; nt < 8; ++nt) {
                    int dl = nt * 16 + lr;
                    float res = b2f(*(unsigned short*)(VTb + dl * 256 + (((m >> 3) ^ (dl & 7)) << 4) + ((m & 7) << 1)));
                    X[(size_t)(b * 100 + m) * 320 + h * 128 + dl] = f2b(O[mi][nt][i] + res);
                }
            }
        }
    }
    if (h == 0) {
        for (int p = 0; p < 25; ++p) {
            int idx = p * 256 + t;
            int m = idx >> 6, d = idx & 63;
            float val = intervals[b * 100 + m] * time_w[d] + time_b[d];
            X[(size_t)(b * 100 + m) * 320 + 256 + d] = f2b(val);
        }
    }
}

// ---------------------------------------------------------------- GRU recurrence + classifier.
// r2/r6-verified flag protocol (438/432 us), with TRANSPOSED MFMA operands: mfma(Wf, af)
// puts C rows = j, C cols = batch, so each thread owns h[1 batch][4 consecutive j]:
//  - publish = ONE dwordx2 (8B) store per thread (256 acks/block vs 1024 -> faster drain)
//  - gi = 3 vectorized s16x4 loads per thread (vs 12 scalar)
//  - hf epilogue = one dwordx4 store
// af loads, flag arm, poll loop are byte-identical to the verified r6 protocol.
// (XCD-team experiment parked after 2 opaque bench failures; data-poll refuted r3/r5.)
__global__ __launch_bounds__(256, 1) void gru_kernel(const unsigned short* GIb, const unsigned short* WHH,
                                                     const float* gbhh, const int* lens,
                                                     unsigned short* hb0, unsigned short* hb1, float* hf,
                                                     int* flags, const float* clsW, const float* clsb, float* out) {
    const int bid = blockIdx.x;
    const int t = threadIdx.x, l = t & 63, w = t >> 6;
    const int lo = l & 15, hi = l >> 4;
    const int d0 = bid * 16;
    const int batch = w * 16 + lo;     // this thread's batch (C col = lane&15)
    const int j0 = d0 + hi * 4;        // this thread's 4 hidden cols (C row = hi*4+i)
    // max length (uniform)
    int ml;
    {
        int v = lens[l];
        v = max(v, __shfl_xor(v, 1));  v = max(v, __shfl_xor(v, 2));
        v = max(v, __shfl_xor(v, 4));  v = max(v, __shfl_xor(v, 8));
        v = max(v, __shfl_xor(v, 16)); v = max(v, __shfl_xor(v, 32));
        ml = v;
    }
    const int len = lens[batch];
    const f32x4 bhr4 = *(const f32x4*)(gbhh + j0);
    const f32x4 bhz4 = *(const f32x4*)(gbhh + 512 + j0);
    const f32x4 bhn4 = *(const f32x4*)(gbhh + 1024 + j0);
    // Whh as A-operand fragments: lane holds W[row j=d0+lo][k = kk*32 + hi*8 + e]
    s16x8 Wf[3][16];
#pragma unroll
    for (int g = 0; g < 3; ++g)
#pragma unroll
        for (int kk = 0; kk < 16; ++kk)
            Wf[g][kk] = *(const s16x8*)(WHH + (size_t)(g * 512 + d0 + lo) * 512 + kk * 32 + hi * 8);
    float ho[4] = {0.f, 0.f, 0.f, 0.f};
    const size_t hrow = (size_t)batch * 512 + j0;          // publish slot (4 shorts, 8B)
    const size_t arow = (size_t)batch * 512 + hi * 8;      // af base (same expr as r6)
    const size_t gi_row = (size_t)batch * 100;             // GIb row base

    // prefetch gi for step 0 (plain cached loads; GIb read-only)
    s16x4 pgr = *(const s16x4*)(GIb + gi_row * 1536 + j0);
    s16x4 pgz = *(const s16x4*)(GIb + gi_row * 1536 + 512 + j0);
    s16x4 pgn = *(const s16x4*)(GIb + gi_row * 1536 + 1024 + j0);

    for (int step = 0; step < ml; ++step) {
        const unsigned short* hb = (step & 1) ? hb1 : hb0;
        unsigned short* hn = (step & 1) ? hb0 : hb1;
        // ---- coherent load of h (B-operand: col = batch, identical addresses to r6)
        s16x8 af[16];
#pragma unroll
        for (int kk = 0; kk < 16; ++kk)
            af[kk] = ld_b128_sc(hb + arow + kk * 32);
        asm volatile("s_waitcnt vmcnt(0)" ::: "memory");
        __builtin_amdgcn_sched_barrier(0);   // keep MFMAs below the wait (asm loads aren't dep-tracked)
        f32x4 ar = (f32x4){0.f,0.f,0.f,0.f}, az = ar, an = ar;
#pragma unroll
        for (int kk = 0; kk < 16; ++kk) {
            ar = __builtin_amdgcn_mfma_f32_16x16x32_bf16(Wf[0][kk], af[kk], ar, 0, 0, 0);
            az = __builtin_amdgcn_mfma_f32_16x16x32_bf16(Wf[1][kk], af[kk], az, 0, 0, 0);
            an = __builtin_amdgcn_mfma_f32_16x16x32_bf16(Wf[2][kk], af[kk], an, 0, 0, 0);
        }
        {
            float hv4[4];
#pragma unroll
            for (int i = 0; i < 4; ++i) {
                float r = sigm(b2f((unsigned short)pgr[i]) + ar[i] + bhr4[i]);
                float z = sigm(b2f((unsigned short)pgz[i]) + az[i] + bhz4[i]);
                float n = tanhf(b2f((unsigned short)pgn[i]) + r * (an[i] + bhn4[i]));
                float hv = (step < len) ? ((1.f - z) * n + z * ho[i]) : ho[i];
                ho[i] = hv; hv4[i] = hv;
            }
            unsigned px = (unsigned)f2b(hv4[0]) | ((unsigned)f2b(hv4[1]) << 16);
            unsigned py = (unsigned)f2b(hv4[2]) | ((unsigned)f2b(hv4[3]) << 16);
            st_b64_sc(hn + hrow, px, py);   // single 8B publish per thread
        }
        // ---- publish: drain store-acks, arm flag, prefetch next gi, wait
        asm volatile("s_waitcnt vmcnt(0)" ::: "memory");
        __syncthreads();
        if (t == 0)
            __hip_atomic_store(flags + bid * 16, step + 1, __ATOMIC_RELAXED, __HIP_MEMORY_SCOPE_AGENT);
        if (step + 1 < ml) {
            pgr = *(const s16x4*)(GIb + (gi_row + step + 1) * 1536 + j0);
            pgz = *(const s16x4*)(GIb + (gi_row + step + 1) * 1536 + 512 + j0);
            pgn = *(const s16x4*)(GIb + (gi_row + step + 1) * 1536 + 1024 + j0);
        }
        if (w == 0) {
            int guard = 0;
            while (true) {
                int v = (l < 32) ? __hip_atomic_load(flags + l * 16, __ATOMIC_RELAXED, __HIP_MEMORY_SCOPE_AGENT) : (step + 1);
                if (__all(v >= step + 1)) break;
                if (++guard > (1 << 20)) break;  // safety: no hang
                __builtin_amdgcn_s_sleep(1);
            }
        }
        __syncthreads();
    }
    // final h (fp32, one 16B coherent store) + classifier
    {
        f32x4 hv = (f32x4){ho[0], ho[1], ho[2], ho[3]};
        st_b128f_sc(hf + (size_t)batch * 512 + j0, hv);
    }
    asm volatile("s_waitcnt vmcnt(0)" ::: "memory");
    __syncthreads();
    if (t == 0)
        __hip_atomic_store(flags + bid * 16, ml + 1, __ATOMIC_RELAXED, __HIP_MEMORY_SCOPE_AGENT);
    if (w == 0) {
        int guard = 0;
        while (true) {
            int v = (l < 32) ? __hip_atomic_load(flags + l * 16, __ATOMIC_RELAXED, __HIP_MEMORY_SCOPE_AGENT) : (ml + 1);
            if (__all(v >= ml + 1)) break;
            if (++guard > (1 << 20)) break;
            __builtin_amdgcn_s_sleep(1);
        }
    }
    __syncthreads();
    if (bid < 30) {
        int bb = t >> 2, qq = t & 3;
        int c0 = bid * 3;
        float s0 = 0.f, s1 = 0.f, s2 = 0.f;
        for (int kc = 0; kc < 32; ++kc) {
            int k = qq * 128 + kc * 4;
            f32x4 hv = *(const f32x4*)(hf + bb * 512 + k);
            f32x4 w0 = *(const f32x4*)(clsW + (c0 + 0) * 512 + k);
            f32x4 w1 = *(const f32x4*)(clsW + (c0 + 1) * 512 + k);
            f32x4 w2 = *(const f32x4*)(clsW + (c0 + 2) * 512 + k);
            s0 += hv[0] * w0[0] + hv[1] * w0[1] + hv[2] * w0[2] + hv[3] * w0[3];
            s1 += hv[0] * w1[0] + hv[1] * w1[1] + hv[2] * w1[2] + hv[3] * w1[3];
            s2 += hv[0] * w2[0] + hv[1] * w2[1] + hv[2] * w2[2] + hv[3] * w2[3];
        }
        s0 += __shfl_xor(s0, 1); s0 += __shfl_xor(s0, 2);
        s1 += __shfl_xor(s1, 1); s1 += __shfl_xor(s1, 2);
        s2 += __shfl_xor(s2, 1); s2 += __shfl_xor(s2, 2);
        if (qq == 0) {
            out[bb * 90 + c0 + 0] = sigm(s0 + clsb[c0 + 0]);
            out[bb * 90 + c0 + 1] = sigm(s1 + clsb[c0 + 1]);
            out[bb * 90 + c0 + 2] = sigm(s2 + clsb[c0 + 2]);
        }
    }
}

// ---------------------------------------------------------------- launch
extern "C" void kernel_launch(void* const* d_in, const int* in_sizes, int n_in,
                              void* d_out, int out_size, void* d_ws, size_t ws_size,
                              hipStream_t stream) {
    const float* code_x   = (const float*)d_in[0];
    const int*   ct0      = (const int*)d_in[1];
    const int*   ct1      = (const int*)d_in[2];
    const int*   ct2      = (const int*)d_in[3];
    const int*   lens     = (const int*)d_in[4];
    const float* intervals= (const float*)d_in[5];
    const float* code_emb = (const float*)d_in[6];
    const float* t0e      = (const float*)d_in[7];
    const float* t1e      = (const float*)d_in[8];
    const float* t2e      = (const float*)d_in[9];
    const float* Wq       = (const float*)d_in[10];
    const float* Wk       = (const float*)d_in[11];
    const float* Wv       = (const float*)d_in[12];
    const float* time_w   = (const float*)d_in[13];
    const float* time_b   = (const float*)d_in[14];
    const float* gWih     = (const float*)d_in[15];
    const float* gWhh     = (const float*)d_in[16];
    const float* gbih     = (const float*)d_in[17];
    const float* gbhh     = (const float*)d_in[18];
    const float* clsW     = (const float*)d_in[19];
    const float* clsb     = (const float*)d_in[20];

    char* ws = (char*)d_ws;
    const size_t ET_OFF   = 0;              // 256*4096*2      = 2,097,152
    const size_t WCAT_OFF = 2097152;        // 512*256*2       =   262,144
    const size_t WIH_OFF  = 2359296;        // 1536*320*2      =   983,040
    const size_t WHH_OFF  = 3342336;        // 1536*512*2      = 1,572,864
    const size_t V_OFF    = 4915200;        // 6400*256*2      = 3,276,800
    const size_t QKV_OFF  = 8192000;        // 6432*512*2      = 6,586,368 (32 pad rows)
    const size_t X_OFF    = 14778368;       // 6400*320*2      = 4,096,000
    const size_t GI_OFF   = 18874368;       // 6400*1536*2     = 19,660,800
    const size_t HB0_OFF  = 38535168;       // 64*512*2        =    65,536
    const size_t HB1_OFF  = 38600704;       // 64*512*2        =    65,536
    const size_t HF_OFF   = 38666240;       // 64*512*4        =   131,072
    const size_t FLG_OFF  = 38797312;       // 1024 ints       =     4,096

    unsigned short* ET   = (unsigned short*)(ws + ET_OFF);
    unsigned short* WCAT = (unsigned short*)(ws + WCAT_OFF);
    unsigned short* WIH  = (unsigned short*)(ws + WIH_OFF);
    unsigned short* WHH  = (unsigned short*)(ws + WHH_OFF);
    unsigned short* Vb   = (unsigned short*)(ws + V_OFF);
    unsigned short* QKV  = (unsigned short*)(ws + QKV_OFF);
    unsigned short* Xb   = (unsigned short*)(ws + X_OFF);
    unsigned short* GIb  = (unsigned short*)(ws + GI_OFF);
    unsigned short* hb0  = (unsigned short*)(ws + HB0_OFF);
    unsigned short* hb1  = (unsigned short*)(ws + HB1_OFF);
    float*          hf   = (float*)(ws + HF_OFF);
    int*            flags= (int*)(ws + FLG_OFF);

    prep_all<<<512, 256, 0, stream>>>(code_emb, ct0, ct1, ct2, t0e, t1e, t2e,
                                      Wq, Wk, Wv, gWih, gWhh,
                                      ET, WCAT, WIH, WHH, flags, hb0);
    enc_gemm<<<200, 256, 0, stream>>>(code_x, ET, lens, Vb);
    gemm_bf16<<<dim3(200, 2), 256, 0, stream>>>(Vb, WCAT, 256, 512, 2, QKV, nullptr);
    attn_kernel<<<dim3(64, 2), 256, 0, stream>>>(QKV, lens, intervals, time_w, time_b, Xb);
    gemm_bf16<<<dim3(200, 6), 256, 0, stream>>>(Xb, WIH, 320, 1536, 1, GIb, gbih);
    gru_kernel<<<32, 256, 0, stream>>>(GIb, WHH, gbhh, lens, hb0, hb1, hf, flags, clsW, clsb, (float*)d_out);
}